// Round 1
// baseline (164.627 us; speedup 1.0000x reference)
//
#include <hip/hip_runtime.h>

// DeformConv2d: x[8,64,56,56], offset[8,18,56,56], weight[64,64,3,3] -> out[8,64,56,56]
// stride 1, pad 1, dil 1, Goff=1, Gw=1.

namespace {
constexpr int Bn = 8, Cn = 64, Hn = 56, Wn = 56;
constexpr int Kk = 9, OCn = 64, OHn = 56, OWn = 56;
constexpr int NPIX = OHn * OWn;        // 3136
constexpr int TP   = 16;               // output pixels per block
constexpr int CK   = Cn * Kk;          // 576
constexpr int VLD  = CK + 4;           // 580 padded LDS row stride (floats)
constexpr int TILES = NPIX / TP;       // 196
}

// Transpose weight [OC][C*K] -> wT [C*K][OC] for coalesced float4 reads in phase 2.
__global__ void wt_kernel(const float* __restrict__ w, float* __restrict__ wT) {
    int i = blockIdx.x * 256 + threadIdx.x;
    if (i < OCn * CK) {
        int oc = i / CK, ck = i % CK;
        wT[ck * OCn + oc] = w[i];
    }
}

__global__ __launch_bounds__(256) void deform_kernel(
    const float* __restrict__ x, const float* __restrict__ off,
    const float* __restrict__ wT, float* __restrict__ out)
{
    __shared__ __align__(16) float v_lds[TP * VLD];   // 37120 B
    __shared__ float4 smpw[Kk * TP];                  // bilinear weights (validity folded)
    __shared__ int4   smpa[Kk * TP];                  // clamped corner offsets within plane

    const int tid = threadIdx.x;
    const int b  = blockIdx.x / TILES;
    const int p0 = (blockIdx.x % TILES) * TP;

    // ---- phase 1a: per-(k,px) sampling coords ----
    if (tid < Kk * TP) {
        const int k  = tid >> 4;
        const int px = tid & 15;
        const int p  = p0 + px;
        const int oy = p / OWn, ox = p % OWn;
        const int ki = k / 3, kj = k % 3;
        const float offy = off[(size_t)(b * 18 + 2 * k)     * NPIX + p];
        const float offx = off[(size_t)(b * 18 + 2 * k + 1) * NPIX + p];
        const float py  = offy + (float)(oy - 1 + ki);
        const float pxv = offx + (float)(ox - 1 + kj);
        const float y0f = floorf(py), x0f = floorf(pxv);
        const float ty = py - y0f, tx = pxv - x0f;
        const int y0 = (int)y0f, x0 = (int)x0f;
        const int y1 = y0 + 1, x1 = x0 + 1;
        const bool vy0 = (y0 >= 0) & (y0 < Hn);
        const bool vy1 = (y1 >= 0) & (y1 < Hn);
        const bool vx0 = (x0 >= 0) & (x0 < Wn);
        const bool vx1 = (x1 >= 0) & (x1 < Wn);
        const int cy0 = min(max(y0, 0), Hn - 1);
        const int cy1 = min(max(y1, 0), Hn - 1);
        const int cx0 = min(max(x0, 0), Wn - 1);
        const int cx1 = min(max(x1, 0), Wn - 1);
        float4 wv;
        wv.x = (vy0 && vx0) ? (1.f - ty) * (1.f - tx) : 0.f;
        wv.y = (vy0 && vx1) ? (1.f - ty) * tx         : 0.f;
        wv.z = (vy1 && vx0) ? ty * (1.f - tx)         : 0.f;
        wv.w = (vy1 && vx1) ? ty * tx                 : 0.f;
        int4 av;
        av.x = cy0 * Wn + cx0;
        av.y = cy0 * Wn + cx1;
        av.z = cy1 * Wn + cx0;
        av.w = cy1 * Wn + cx1;
        smpw[tid] = wv;
        smpa[tid] = av;
    }
    __syncthreads();

    // ---- phase 1b: gather v[c*K+k][px] into LDS (layout [px][ck], padded) ----
    const float* xb = x + (size_t)b * Cn * NPIX;
    for (int s = tid; s < CK * TP; s += 256) {
        const int px = s & 15;
        const int ck = s >> 4;
        const int c  = ck / 9;
        const int k  = ck - c * 9;
        const int j  = k * TP + px;
        const float4 wv = smpw[j];
        const int4   av = smpa[j];
        const float* xc = xb + (size_t)c * NPIX;
        const float v = wv.x * xc[av.x] + wv.y * xc[av.y]
                      + wv.z * xc[av.z] + wv.w * xc[av.w];
        v_lds[px * VLD + ck] = v;
    }
    __syncthreads();

    // ---- phase 2: out[oc][px] = sum_ck wT[ck][oc] * v[px][ck] ----
    const int px  = tid & 15;
    const int ocb = (tid >> 4) << 2;   // 4 consecutive oc per thread
    const float* vrow = &v_lds[px * VLD];
    float a0 = 0.f, a1 = 0.f, a2 = 0.f, a3 = 0.f;
    for (int ck = 0; ck < CK; ck += 4) {
        const float4 v4 = *(const float4*)(vrow + ck);
        const float4 w0 = *(const float4*)(wT + (size_t)(ck + 0) * OCn + ocb);
        const float4 w1 = *(const float4*)(wT + (size_t)(ck + 1) * OCn + ocb);
        const float4 w2 = *(const float4*)(wT + (size_t)(ck + 2) * OCn + ocb);
        const float4 w3 = *(const float4*)(wT + (size_t)(ck + 3) * OCn + ocb);
        a0 += v4.x * w0.x + v4.y * w1.x + v4.z * w2.x + v4.w * w3.x;
        a1 += v4.x * w0.y + v4.y * w1.y + v4.z * w2.y + v4.w * w3.y;
        a2 += v4.x * w0.z + v4.y * w1.z + v4.z * w2.z + v4.w * w3.z;
        a3 += v4.x * w0.w + v4.y * w1.w + v4.z * w2.w + v4.w * w3.w;
    }
    float* op = out + ((size_t)b * OCn + ocb) * NPIX + p0 + px;
    op[0 * NPIX] = a0;
    op[1 * NPIX] = a1;
    op[2 * NPIX] = a2;
    op[3 * NPIX] = a3;
}

extern "C" void kernel_launch(void* const* d_in, const int* in_sizes, int n_in,
                              void* d_out, int out_size, void* d_ws, size_t ws_size,
                              hipStream_t stream) {
    const float* x   = (const float*)d_in[0];
    const float* off = (const float*)d_in[1];
    const float* w   = (const float*)d_in[2];
    float* out = (float*)d_out;
    float* wT  = (float*)d_ws;   // 576*64*4 = 147456 B

    hipLaunchKernelGGL(wt_kernel, dim3((OCn * CK + 255) / 256), dim3(256), 0, stream, w, wT);
    hipLaunchKernelGGL(deform_kernel, dim3(Bn * TILES), dim3(256), 0, stream,
                       x, off, wT, out);
}

// Round 2
// 67.473 us; speedup vs baseline: 2.4399x; 2.4399x over previous
//
#include <hip/hip_runtime.h>

// DeformConv2d: x[8,64,56,56], offset[8,18,56,56], weight[64,64,3,3] -> out[8,64,56,56]
// stride 1, pad 1, dil 1, Goff=1, Gw=1. GEMM phase via bf16 MFMA.

typedef short bf16x8 __attribute__((ext_vector_type(8)));   // 8 bf16 in 4 VGPRs
typedef float f32x4  __attribute__((ext_vector_type(4)));

namespace {
constexpr int Bn = 8, Cn = 64, Hn = 56, Wn = 56;
constexpr int Kk = 9, OCn = 64;
constexpr int NPIX = 56 * 56;      // 3136
constexpr int CK   = Cn * Kk;      // 576
constexpr int TP   = 32;           // output pixels per block
constexpr int TILES = NPIX / TP;   // 98
constexpr int KSTEPS = CK / 32;    // 18
}

__device__ __forceinline__ unsigned short f2bf(float f) {
    unsigned u = __float_as_uint(f);
    u += 0x7fffu + ((u >> 16) & 1u);   // round-to-nearest-even
    return (unsigned short)(u >> 16);
}

// weight [OC][C*K] fp32 -> bf16 (row-major; A-fragment reads are 16B contiguous)
__global__ void prep_kernel(const float* __restrict__ w, unsigned short* __restrict__ wbf) {
    int i = blockIdx.x * 256 + threadIdx.x;
    if (i < OCn * CK) wbf[i] = f2bf(w[i]);
}

__global__ __launch_bounds__(256) void deform_kernel(
    const float* __restrict__ x, const float* __restrict__ off,
    const unsigned short* __restrict__ wbf, float* __restrict__ out)
{
    // v tile in MFMA-B-native layout: [ck/8][px][8 consecutive ck] bf16
    __shared__ __align__(16) unsigned short v_lds[CK / 8][TP][8];   // 36864 B
    __shared__ float4 smpw[Kk * TP];   // bilinear corner weights (validity folded)
    __shared__ int4   smpa[Kk * TP];   // clamped corner offsets within HxW plane

    const int tid = threadIdx.x;
    const int b  = blockIdx.x / TILES;
    const int p0 = (blockIdx.x % TILES) * TP;

    // ---- phase 1a: per-(k,px) sampling coords ----
    for (int t = tid; t < Kk * TP; t += 256) {
        const int k  = t >> 5;
        const int px = t & 31;
        const int p  = p0 + px;
        const int oy = p / Wn, ox = p % Wn;
        const int ki = k / 3, kj = k % 3;
        const float offy = off[(size_t)(b * 18 + 2 * k)     * NPIX + p];
        const float offx = off[(size_t)(b * 18 + 2 * k + 1) * NPIX + p];
        const float py  = offy + (float)(oy - 1 + ki);
        const float pxv = offx + (float)(ox - 1 + kj);
        const float y0f = floorf(py), x0f = floorf(pxv);
        const float ty = py - y0f, tx = pxv - x0f;
        const int y0 = (int)y0f, x0 = (int)x0f;
        const int y1 = y0 + 1, x1 = x0 + 1;
        const bool vy0 = (y0 >= 0) & (y0 < Hn);
        const bool vy1 = (y1 >= 0) & (y1 < Hn);
        const bool vx0 = (x0 >= 0) & (x0 < Wn);
        const bool vx1 = (x1 >= 0) & (x1 < Wn);
        const int cy0 = min(max(y0, 0), Hn - 1);
        const int cy1 = min(max(y1, 0), Hn - 1);
        const int cx0 = min(max(x0, 0), Wn - 1);
        const int cx1 = min(max(x1, 0), Wn - 1);
        float4 wv;
        wv.x = (vy0 && vx0) ? (1.f - ty) * (1.f - tx) : 0.f;
        wv.y = (vy0 && vx1) ? (1.f - ty) * tx         : 0.f;
        wv.z = (vy1 && vx0) ? ty * (1.f - tx)         : 0.f;
        wv.w = (vy1 && vx1) ? ty * tx                 : 0.f;
        int4 av;
        av.x = cy0 * Wn + cx0;
        av.y = cy0 * Wn + cx1;
        av.z = cy1 * Wn + cx0;
        av.w = cy1 * Wn + cx1;
        smpw[t] = wv;
        smpa[t] = av;
    }
    __syncthreads();

    // ---- phase 1b: bilinear gather -> bf16 -> LDS (8 ck per thread-iter, 16B write) ----
    const float* xb = x + (size_t)b * Cn * NPIX;
    for (int s = tid; s < (CK / 8) * TP; s += 256) {   // 2304 / 256 = 9 iters
        const int px = s & 31;
        const int g  = s >> 5;
        unsigned short pack[8] __attribute__((aligned(16)));
        #pragma unroll
        for (int j = 0; j < 8; ++j) {
            const int ck = g * 8 + j;
            const int c  = ck / 9;
            const int k  = ck - c * 9;
            const float4 wv = smpw[k * TP + px];
            const int4   av = smpa[k * TP + px];
            const float* xc = xb + c * NPIX;
            pack[j] = f2bf(wv.x * xc[av.x] + wv.y * xc[av.y]
                         + wv.z * xc[av.z] + wv.w * xc[av.w]);
        }
        *reinterpret_cast<uint4*>(&v_lds[g][px][0]) = *reinterpret_cast<const uint4*>(pack);
    }
    __syncthreads();

    // ---- phase 2: MFMA GEMM. D[oc 64][px 32] = W[64][576] x V[576][32] ----
    const int lane = tid & 63;
    const int wid  = tid >> 6;     // wave id: oc block of 16
    const int lr   = lane & 15;    // A: row (oc), B: col (px), D: col (px)
    const int lk   = lane >> 4;    // k-group (8 consecutive k)
    const unsigned short* wrow = wbf + (size_t)(wid * 16 + lr) * CK + lk * 8;
    f32x4 acc0 = {0.f, 0.f, 0.f, 0.f};
    f32x4 acc1 = {0.f, 0.f, 0.f, 0.f};
    #pragma unroll
    for (int kk = 0; kk < KSTEPS; ++kk) {
        const bf16x8 a  = *reinterpret_cast<const bf16x8*>(wrow + kk * 32);
        const bf16x8 b0 = *reinterpret_cast<const bf16x8*>(&v_lds[kk * 4 + lk][lr][0]);
        const bf16x8 b1 = *reinterpret_cast<const bf16x8*>(&v_lds[kk * 4 + lk][16 + lr][0]);
        acc0 = __builtin_amdgcn_mfma_f32_16x16x32_bf16(a, b0, acc0, 0, 0, 0);
        acc1 = __builtin_amdgcn_mfma_f32_16x16x32_bf16(a, b1, acc1, 0, 0, 0);
    }
    // D mapping: col(px) = lane&15, row(oc within 16) = (lane>>4)*4 + reg
    float* ob = out + ((size_t)b * OCn + wid * 16 + lk * 4) * NPIX + p0 + lr;
    #pragma unroll
    for (int r = 0; r < 4; ++r) {
        ob[(size_t)r * NPIX]      = acc0[r];
        ob[(size_t)r * NPIX + 16] = acc1[r];
    }
}

extern "C" void kernel_launch(void* const* d_in, const int* in_sizes, int n_in,
                              void* d_out, int out_size, void* d_ws, size_t ws_size,
                              hipStream_t stream) {
    const float* x   = (const float*)d_in[0];
    const float* off = (const float*)d_in[1];
    const float* w   = (const float*)d_in[2];
    float* out = (float*)d_out;
    unsigned short* wbf = (unsigned short*)d_ws;   // 576*64*2 = 73728 B

    hipLaunchKernelGGL(prep_kernel, dim3((OCn * CK + 255) / 256), dim3(256), 0, stream, w, wbf);
    hipLaunchKernelGGL(deform_kernel, dim3(Bn * TILES), dim3(256), 0, stream,
                       x, off, wbf, out);
}

// Round 3
// 45.526 us; speedup vs baseline: 3.6161x; 1.4821x over previous
//
#include <hip/hip_runtime.h>

// DeformConv2d: x[8,64,56,56], offset[8,18,56,56], weight[64,64,3,3] -> out[8,64,56,56]
// stride 1, pad 1, dil 1. Gather from NHWC-bf16 x; k-major GEMM via bf16 MFMA.

typedef short  bf16x8 __attribute__((ext_vector_type(8)));
typedef float  f32x4  __attribute__((ext_vector_type(4)));
typedef unsigned short ushortx8 __attribute__((ext_vector_type(8)));

namespace {
constexpr int Bn = 8, Cn = 64, Hn = 56, Wn = 56;
constexpr int Kk = 9, OCn = 64;
constexpr int NPIX = 56 * 56;      // 3136
constexpr int CK   = Cn * Kk;      // 576
constexpr int TP   = 16;           // output pixels per block
constexpr int TILES = NPIX / TP;   // 196
constexpr int KSTEPS = CK / 32;    // 18
constexpr int GU   = TP * (CK / 8);  // 1152 gather units per block
}

__device__ __forceinline__ unsigned short f2bf(float f) {
    unsigned u = __float_as_uint(f);
    u += 0x7fffu + ((u >> 16) & 1u);   // RNE
    return (unsigned short)(u >> 16);
}
__device__ __forceinline__ float bf2f(unsigned short h) {
    return __uint_as_float((unsigned)h << 16);
}

// weight [OC][C][K] fp32 -> wbf[oc][k*64+c] bf16 (k-major K ordering)
__global__ void prep_w(const float* __restrict__ w, unsigned short* __restrict__ wbf) {
    int i = blockIdx.x * 256 + threadIdx.x;
    if (i < OCn * CK) {
        int oc = i / CK, r = i % CK;
        int c = r / Kk, k = r % Kk;
        wbf[oc * CK + k * Cn + c] = f2bf(w[i]);
    }
}

// x [B][C][HW] fp32 -> xh [B][HW][C] bf16 via LDS transpose tile (64 hw x 64 c)
__global__ __launch_bounds__(256) void prep_x(const float* __restrict__ x,
                                              unsigned short* __restrict__ xh) {
    __shared__ unsigned short lds[64 * 68];
    const int tid = threadIdx.x;
    const int b  = blockIdx.x / 49;
    const int t0 = (blockIdx.x % 49) * 64;
    const float* xb = x + (size_t)b * Cn * NPIX;
    const int hw = tid & 63;
    #pragma unroll
    for (int i = 0; i < 16; ++i) {
        const int c = (tid >> 6) + i * 4;
        lds[hw * 68 + c] = f2bf(xb[(size_t)c * NPIX + t0 + hw]);
    }
    __syncthreads();
    unsigned short* ob = xh + ((size_t)b * NPIX + t0) * Cn;
    const int c = tid & 63;
    #pragma unroll
    for (int i = 0; i < 16; ++i) {
        const int h2 = (tid >> 6) + i * 4;
        ob[(size_t)h2 * Cn + c] = lds[h2 * 68 + c];
    }
}

__global__ __launch_bounds__(256) void deform_kernel(
    const unsigned short* __restrict__ xh, const float* __restrict__ off,
    const unsigned short* __restrict__ wbf, float* __restrict__ out)
{
    // v tile, MFMA-B-native: [ck'/8][px][8 consecutive ck'] bf16, ck' = k*64+c
    __shared__ __align__(16) unsigned short v_lds[CK / 8][TP][8];   // 18432 B

    const int tid = threadIdx.x;
    const int b  = blockIdx.x / TILES;
    const int p0 = (blockIdx.x % TILES) * TP;
    const unsigned short* xb = xh + (size_t)b * NPIX * Cn;
    const float* offb = off + (size_t)b * 18 * NPIX;

    // ---- gather: unit = (px, k, channel-octet) ----
    for (int u = tid; u < GU; u += 256) {
        const int px  = u & (TP - 1);
        const int q   = u >> 4;        // 0..71
        const int k   = q >> 3;
        const int oct = q & 7;
        const int p  = p0 + px;
        const int oy = p / Wn, ox = p % Wn;
        const int ki = k / 3, kj = k % 3;
        const float offy = offb[(size_t)(2 * k)     * NPIX + p];
        const float offx = offb[(size_t)(2 * k + 1) * NPIX + p];
        const float py  = offy + (float)(oy - 1 + ki);
        const float pxv = offx + (float)(ox - 1 + kj);
        const float y0f = floorf(py), x0f = floorf(pxv);
        const float ty = py - y0f, tx = pxv - x0f;
        const int y0 = (int)y0f, x0 = (int)x0f;
        const int y1 = y0 + 1, x1 = x0 + 1;
        const bool vy0 = (y0 >= 0) & (y0 < Hn);
        const bool vy1 = (y1 >= 0) & (y1 < Hn);
        const bool vx0 = (x0 >= 0) & (x0 < Wn);
        const bool vx1 = (x1 >= 0) & (x1 < Wn);
        const int cy0 = min(max(y0, 0), Hn - 1);
        const int cy1 = min(max(y1, 0), Hn - 1);
        const int cx0 = min(max(x0, 0), Wn - 1);
        const int cx1 = min(max(x1, 0), Wn - 1);
        const float w00 = (vy0 && vx0) ? (1.f - ty) * (1.f - tx) : 0.f;
        const float w01 = (vy0 && vx1) ? (1.f - ty) * tx         : 0.f;
        const float w10 = (vy1 && vx0) ? ty * (1.f - tx)         : 0.f;
        const float w11 = (vy1 && vx1) ? ty * tx                 : 0.f;
        const int co = oct * 8;
        const ushortx8 s00 = *(const ushortx8*)(xb + ((size_t)(cy0 * Wn + cx0) * Cn + co));
        const ushortx8 s01 = *(const ushortx8*)(xb + ((size_t)(cy0 * Wn + cx1) * Cn + co));
        const ushortx8 s10 = *(const ushortx8*)(xb + ((size_t)(cy1 * Wn + cx0) * Cn + co));
        const ushortx8 s11 = *(const ushortx8*)(xb + ((size_t)(cy1 * Wn + cx1) * Cn + co));
        unsigned short pack[8] __attribute__((aligned(16)));
        #pragma unroll
        for (int j = 0; j < 8; ++j) {
            const float v = w00 * bf2f(s00[j]) + w01 * bf2f(s01[j])
                          + w10 * bf2f(s10[j]) + w11 * bf2f(s11[j]);
            pack[j] = f2bf(v);
        }
        *reinterpret_cast<uint4*>(&v_lds[q][px][0]) = *reinterpret_cast<const uint4*>(pack);
    }
    __syncthreads();

    // ---- GEMM: wave wid -> D[oc 16][px 16]; K swept k-major ----
    const int lane = tid & 63;
    const int wid  = tid >> 6;
    const int lr   = lane & 15;    // A: row (oc); B/D: col (px)
    const int lk   = lane >> 4;    // k-group of 8
    const unsigned short* wrow = wbf + (size_t)(wid * 16 + lr) * CK + lk * 8;
    f32x4 acc = {0.f, 0.f, 0.f, 0.f};
    #pragma unroll
    for (int kk = 0; kk < KSTEPS; ++kk) {
        const bf16x8 a = *reinterpret_cast<const bf16x8*>(wrow + kk * 32);
        const bf16x8 bb = *reinterpret_cast<const bf16x8*>(&v_lds[kk * 4 + lk][lr][0]);
        acc = __builtin_amdgcn_mfma_f32_16x16x32_bf16(a, bb, acc, 0, 0, 0);
    }
    // D: col(px)=lane&15, row(oc within 16) = (lane>>4)*4 + r
    float* ob = out + ((size_t)b * OCn + wid * 16 + lk * 4) * NPIX + p0 + lr;
    #pragma unroll
    for (int r = 0; r < 4; ++r) ob[(size_t)r * NPIX] = acc[r];
}

extern "C" void kernel_launch(void* const* d_in, const int* in_sizes, int n_in,
                              void* d_out, int out_size, void* d_ws, size_t ws_size,
                              hipStream_t stream) {
    const float* x   = (const float*)d_in[0];
    const float* off = (const float*)d_in[1];
    const float* w   = (const float*)d_in[2];
    float* out = (float*)d_out;
    unsigned short* wbf = (unsigned short*)d_ws;                       // 73728 B
    unsigned short* xh  = (unsigned short*)((char*)d_ws + 131072);     // 3.21 MB

    hipLaunchKernelGGL(prep_w, dim3((OCn * CK + 255) / 256), dim3(256), 0, stream, w, wbf);
    hipLaunchKernelGGL(prep_x, dim3(Bn * 49), dim3(256), 0, stream, x, xh);
    hipLaunchKernelGGL(deform_kernel, dim3(Bn * TILES), dim3(256), 0, stream,
                       xh, off, wbf, out);
}

// Round 4
// 40.416 us; speedup vs baseline: 4.0733x; 1.1264x over previous
//
#include <hip/hip_runtime.h>
#include <hip/hip_fp16.h>

// DeformConv2d: x[8,64,56,56], offset[8,18,56,56], weight[64,64,3,3] -> out[8,64,56,56]
// stride 1, pad 1, dil 1. NHWC-fp16 x; packed-fp16 bilinear gather; k-major fp16 MFMA GEMM.

typedef _Float16 f16x8 __attribute__((ext_vector_type(8)));
typedef float    f32x4 __attribute__((ext_vector_type(4)));

namespace {
constexpr int Bn = 8, Cn = 64, Hn = 56, Wn = 56;
constexpr int Kk = 9, OCn = 64;
constexpr int NPIX = 56 * 56;      // 3136
constexpr int CK   = Cn * Kk;      // 576
constexpr int TP   = 16;           // output pixels per block
constexpr int TILES = NPIX / TP;   // 196
constexpr int KSTEPS = CK / 32;    // 18
constexpr int XTILES = NPIX / 64;  // 49 transpose tiles per batch
}

__device__ __forceinline__ __half2 u2h(unsigned u) {
    union { unsigned u; __half2 h; } x; x.u = u; return x.h;
}
__device__ __forceinline__ unsigned bcast_h(float f) {
    unsigned short hs = __half_as_ushort(__float2half(f));
    return (unsigned)hs * 0x10001u;
}

// Fused prep: blocks [0,392): x NCHW fp32 -> NHWC fp16 (64hw x 64c LDS transpose tile).
//             blocks [392,536): weight [OC][C][K] fp32 -> fp16 [oc][k*64+c].
__global__ __launch_bounds__(256) void prep_kernel(
    const float* __restrict__ x, const float* __restrict__ w,
    unsigned short* __restrict__ xh, unsigned short* __restrict__ wh)
{
    const int tid = threadIdx.x;
    if (blockIdx.x >= 392) {
        const int i = (blockIdx.x - 392) * 256 + tid;
        if (i < OCn * CK) {
            const int oc = i / CK, r = i % CK;
            const int c = r / Kk, k = r % Kk;
            wh[oc * CK + k * Cn + c] = __half_as_ushort(__float2half(w[i]));
        }
        return;
    }
    __shared__ unsigned short lds[64][66];
    const int b  = blockIdx.x / XTILES;
    const int t0 = (blockIdx.x % XTILES) * 64;
    const float* xb = x + (size_t)b * Cn * NPIX;
    {
        const int hw0 = (tid & 15) * 4;
        #pragma unroll
        for (int i = 0; i < 4; ++i) {
            const int c = (tid >> 4) + i * 16;
            const float4 v = *(const float4*)(xb + (size_t)c * NPIX + t0 + hw0);
            lds[hw0 + 0][c] = __half_as_ushort(__float2half(v.x));
            lds[hw0 + 1][c] = __half_as_ushort(__float2half(v.y));
            lds[hw0 + 2][c] = __half_as_ushort(__float2half(v.z));
            lds[hw0 + 3][c] = __half_as_ushort(__float2half(v.w));
        }
    }
    __syncthreads();
    {
        const int co = (tid & 7) * 8;
        #pragma unroll
        for (int i = 0; i < 2; ++i) {
            const int hw = (tid >> 3) + i * 32;
            unsigned short tmp[8] __attribute__((aligned(16)));
            #pragma unroll
            for (int j = 0; j < 8; ++j) tmp[j] = lds[hw][co + j];
            *(uint4*)(xh + ((size_t)b * NPIX + t0 + hw) * Cn + co) = *(const uint4*)tmp;
        }
    }
}

__global__ __launch_bounds__(256) void deform_kernel(
    const unsigned short* __restrict__ xh, const float* __restrict__ off,
    const unsigned short* __restrict__ wh, float* __restrict__ out)
{
    // v tile, MFMA-B-native: [ck'/8][px][8 halves], ck' = k*64 + c
    __shared__ __align__(16) unsigned short v_lds[CK / 8][TP][8];   // 18432 B
    __shared__ uint4 smpw[Kk * TP];   // 4 bilinear weights, each broadcast-packed half2
    __shared__ int4  smpa[Kk * TP];   // 4 corner offsets, pre-scaled by Cn

    const int tid = threadIdx.x;
    const int b  = blockIdx.x / TILES;
    const int p0 = (blockIdx.x % TILES) * TP;
    const unsigned short* xb = xh + (size_t)b * NPIX * Cn;
    const float* offb = off + (size_t)b * 18 * NPIX;

    // ---- metadata: one entry per (k, px) ----
    if (tid < Kk * TP) {
        const int k  = tid >> 4;
        const int px = tid & 15;
        const int p  = p0 + px;
        const int oy = p / Wn, ox = p % Wn;
        const int ki = k / 3, kj = k % 3;
        const float offy = offb[(size_t)(2 * k)     * NPIX + p];
        const float offx = offb[(size_t)(2 * k + 1) * NPIX + p];
        const float py  = offy + (float)(oy - 1 + ki);
        const float pxv = offx + (float)(ox - 1 + kj);
        const float y0f = floorf(py), x0f = floorf(pxv);
        const float ty = py - y0f, tx = pxv - x0f;
        const int y0 = (int)y0f, x0 = (int)x0f;
        const int y1 = y0 + 1, x1 = x0 + 1;
        const bool vy0 = (y0 >= 0) & (y0 < Hn);
        const bool vy1 = (y1 >= 0) & (y1 < Hn);
        const bool vx0 = (x0 >= 0) & (x0 < Wn);
        const bool vx1 = (x1 >= 0) & (x1 < Wn);
        const int cy0 = min(max(y0, 0), Hn - 1);
        const int cy1 = min(max(y1, 0), Hn - 1);
        const int cx0 = min(max(x0, 0), Wn - 1);
        const int cx1 = min(max(x1, 0), Wn - 1);
        uint4 wq;
        wq.x = bcast_h((vy0 && vx0) ? (1.f - ty) * (1.f - tx) : 0.f);
        wq.y = bcast_h((vy0 && vx1) ? (1.f - ty) * tx         : 0.f);
        wq.z = bcast_h((vy1 && vx0) ? ty * (1.f - tx)         : 0.f);
        wq.w = bcast_h((vy1 && vx1) ? ty * tx                 : 0.f);
        int4 av;
        av.x = (cy0 * Wn + cx0) * Cn;
        av.y = (cy0 * Wn + cx1) * Cn;
        av.z = (cy1 * Wn + cx0) * Cn;
        av.w = (cy1 * Wn + cx1) * Cn;
        smpw[tid] = wq;
        smpa[tid] = av;
    }
    __syncthreads();

    // ---- gather: unit = (px, k, channel-octet); 1152 units, fully unrolled ----
    auto gather = [&](int u) {
        const int px  = u & (TP - 1);
        const int q   = u >> 4;        // 0..71
        const int k   = q >> 3;
        const int co  = (q & 7) * 8;
        const int m   = k * TP + px;
        const uint4 wq = smpw[m];
        const int4  av = smpa[m];
        const uint4 s00 = *(const uint4*)(xb + av.x + co);
        const uint4 s01 = *(const uint4*)(xb + av.y + co);
        const uint4 s10 = *(const uint4*)(xb + av.z + co);
        const uint4 s11 = *(const uint4*)(xb + av.w + co);
        const __half2 w00 = u2h(wq.x), w01 = u2h(wq.y), w10 = u2h(wq.z), w11 = u2h(wq.w);
        unsigned res[4] __attribute__((aligned(16)));
        #pragma unroll
        for (int j = 0; j < 4; ++j) {
            __half2 a = __hmul2(w00, u2h(((const unsigned*)&s00)[j]));
            a = __hfma2(w01, u2h(((const unsigned*)&s01)[j]), a);
            a = __hfma2(w10, u2h(((const unsigned*)&s10)[j]), a);
            a = __hfma2(w11, u2h(((const unsigned*)&s11)[j]), a);
            res[j] = *(const unsigned*)&a;
        }
        *(uint4*)(&v_lds[q][px][0]) = *(const uint4*)res;
    };
    #pragma unroll
    for (int i = 0; i < 4; ++i) gather(tid + 256 * i);
    if (tid < 128) gather(tid + 1024);
    __syncthreads();

    // ---- GEMM: wave wid -> D[oc 16][px 16]; K swept k-major ----
    const int lane = tid & 63;
    const int wid  = tid >> 6;
    const int lr   = lane & 15;    // A: row (oc); B/D: col (px)
    const int lk   = lane >> 4;    // k-group of 8
    const unsigned short* wrow = wh + (size_t)(wid * 16 + lr) * CK + lk * 8;
    f32x4 acc = {0.f, 0.f, 0.f, 0.f};
    #pragma unroll
    for (int kk = 0; kk < KSTEPS; ++kk) {
        const f16x8 a  = *reinterpret_cast<const f16x8*>(wrow + kk * 32);
        const f16x8 bb = *reinterpret_cast<const f16x8*>(&v_lds[kk * 4 + lk][lr][0]);
        acc = __builtin_amdgcn_mfma_f32_16x16x32_f16(a, bb, acc, 0, 0, 0);
    }
    float* ob = out + ((size_t)b * OCn + wid * 16 + lk * 4) * NPIX + p0 + lr;
    #pragma unroll
    for (int r = 0; r < 4; ++r) ob[(size_t)r * NPIX] = acc[r];
}

extern "C" void kernel_launch(void* const* d_in, const int* in_sizes, int n_in,
                              void* d_out, int out_size, void* d_ws, size_t ws_size,
                              hipStream_t stream) {
    const float* x   = (const float*)d_in[0];
    const float* off = (const float*)d_in[1];
    const float* w   = (const float*)d_in[2];
    float* out = (float*)d_out;
    unsigned short* wh = (unsigned short*)d_ws;                     // 73728 B
    unsigned short* xh = (unsigned short*)((char*)d_ws + 131072);   // 3.21 MB

    hipLaunchKernelGGL(prep_kernel, dim3(392 + 144), dim3(256), 0, stream, x, w, xh, wh);
    hipLaunchKernelGGL(deform_kernel, dim3(Bn * TILES), dim3(256), 0, stream,
                       xh, off, wh, out);
}